// Round 5
// baseline (13.472 us; speedup 1.0000x reference)
//
#include <hip/hip_runtime.h>
#include <stdint.h>

#define OUTHW 511
#define IMGW 512

// ============ compile-time numpy RandomState(42) replication ============
struct COps { int n; int kind[64]; int wa[64]; int wb[64]; int widx[64]; };

struct CMT {
    uint32_t mt[624]; int mti;
    constexpr CMT(uint32_t s) : mt{}, mti(624) {
        mt[0] = s;
        for (int i = 1; i < 624; ++i)
            mt[i] = 1812433253u * (mt[i - 1] ^ (mt[i - 1] >> 30)) + (uint32_t)i;
    }
    constexpr uint32_t next32() {
        if (mti >= 624) {
            for (int i = 0; i < 624; ++i) {
                uint32_t y = (mt[i] & 0x80000000u) | (mt[(i + 1) % 624] & 0x7fffffffu);
                mt[i] = mt[(i + 397) % 624] ^ (y >> 1) ^ ((y & 1u) ? 0x9908b0dfu : 0u);
            }
            mti = 0;
        }
        uint32_t y = mt[mti++];
        y ^= y >> 11; y ^= (y << 7) & 0x9d2c5680u; y ^= (y << 15) & 0xefc60000u; y ^= y >> 18;
        return y;
    }
    constexpr double rand_double() {  // random_sample(): 2 draws
        uint32_t a = next32() >> 5, b = next32() >> 6;
        return (a * 67108864.0 + b) / 9007199254740992.0;
    }
    constexpr uint32_t interval(uint32_t mx) {  // legacy masked randint
        if (mx == 0) return 0;
        uint32_t mask = mx;
        mask |= mask >> 1; mask |= mask >> 2; mask |= mask >> 4;
        mask |= mask >> 8; mask |= mask >> 16;
        uint32_t v = next32() & mask;
        while (v > mx) v = next32() & mask;
        return v;
    }
};

constexpr COps build_ops_ce() {
    CMT mt(42u); COps P{}; P.n = 0;
    for (int l = 0; l < 2; ++l) {
        int i = 0;
        while (i < 4 && P.n < 64) {
            if (mt.rand_double() > 0.3) {
                int g = (int)mt.interval(2);  // randint(3)
                int w = (int)mt.interval(3);  // randint(4)
                P.kind[P.n] = g; P.wa[P.n] = w; P.wb[P.n] = 0; P.widx[P.n] = l * 4 + i;
                ++P.n; ++i;
            } else {  // choice(4,2,replace=False) == permutation(4)[:2]
                int arr[4] = {0, 1, 2, 3};
                for (int ii = 3; ii >= 1; --ii) {
                    int j = (int)mt.interval((uint32_t)ii);
                    int t = arr[ii]; arr[ii] = arr[j]; arr[j] = t;
                }
                P.kind[P.n] = 3; P.wa[P.n] = arr[0]; P.wb[P.n] = arr[1]; P.widx[P.n] = -1;
                ++P.n;
            }
        }
    }
    return P;
}
constexpr COps OPS = build_ops_ce();

// ===== compile-time Heisenberg support: which W_j[t] can be nonzero =====
struct Tabs {
    bool u[81];        // union support over j
    bool mj[4][81];    // per-output support
    int nu;            // |union|
    int tlist[81];     // compacted union t list
    int zm[81], xm[81];// stage-2 state-index masks per t
};

constexpr Tabs build_tabs() {
    Tabs T{};
    for (int j = 0; j < 4; ++j) {
        bool cur[256] = {};
        cur[1 << (4 + j)] = true;  // Z_j
        for (int o = OPS.n - 1; o >= 0; --o) {
            bool nxt[256] = {};
            for (int c = 0; c < 256; ++c) if (cur[c]) {
                if (OPS.kind[o] == 3) {  // CNOT: x_t ^= x_c ; z_c ^= z_t
                    int cc = OPS.wa[o], tt = OPS.wb[o], nc = c;
                    if (c & (1 << cc))       nc ^= (1 << tt);
                    if (c & (1 << (4 + tt))) nc ^= (1 << (4 + cc));
                    nxt[nc] = true;
                } else {
                    int w = OPS.wa[o];
                    int xw = (c >> w) & 1, zw = (c >> (4 + w)) & 1;
                    bool anti = false; int pm = 0;
                    if (OPS.kind[o] == 0)      { anti = zw != 0;        pm = 1 << w; }                    // RX
                    else if (OPS.kind[o] == 1) { anti = (xw ^ zw) != 0; pm = (1 << w) | (1 << (4 + w)); } // RY
                    else                       { anti = xw != 0;        pm = 1 << (4 + w); }              // RZ
                    nxt[c] = true;
                    if (anti) nxt[c ^ pm] = true;
                }
            }
            for (int c = 0; c < 256; ++c) cur[c] = nxt[c];
        }
        for (int c = 0; c < 256; ++c) if (cur[c]) {
            bool hasY = false; int t = 0;
            for (int k = 0; k < 4; ++k) {
                int xk = (c >> k) & 1, zk = (c >> (4 + k)) & 1;
                if (xk && zk) hasY = true;            // <Y> = 0 for real product state
                t = t * 3 + (zk ? 1 : (xk ? 2 : 0));  // qubit k at place 3^(3-k)
            }
            if (!hasY) { T.mj[j][t] = true; T.u[t] = true; }
        }
    }
    T.nu = 0;
    for (int t = 0; t < 81; ++t) {
        int dd[4] = {t / 27, (t / 9) % 3, (t / 3) % 3, t % 3};
        int zm = 0, xm = 0;
        for (int k = 0; k < 4; ++k) {
            int p = 3 - k;
            if (dd[k] == 1) zm |= 1 << p;
            else if (dd[k] == 2) xm |= 1 << p;
        }
        T.zm[t] = zm; T.xm[t] = xm;
        if (T.u[t]) T.tlist[T.nu++] = t;
    }
    return T;
}
constexpr Tabs TB = build_tabs();
constexpr int NU = TB.nu;

// 4 outputs x 81 monomial coefficients over {1, cos(pi x_k), sin(pi x_k)}^4
__device__ float g_W[4 * 81];

// One block of 512. Straight-line (compile-time ops) circuit sim + table.
__global__ void __launch_bounds__(512) build_table(const float* __restrict__ wts) {
    __shared__ float Ur[256];     // [b*16+n] = Re U[n][b]
    __shared__ float Ui[256];
    __shared__ float S[81 * 16];  // stage-2 partials per (t,n)
    const int tid = threadIdx.x;
    if (tid < 256) {
        Ur[tid] = ((tid >> 4) == (tid & 15)) ? 1.f : 0.f;
        Ui[tid] = 0.f;
    }
    __syncthreads();
    const float INV4PI = 0.07957747154594767f;  // 1/(4*pi)
#pragma unroll
    for (int o = 0; o < OPS.n; ++o) {
        if (OPS.kind[o] == 3) {  // CNOT — wires compile-time
            const int pc = 3 - OPS.wa[o], pt = 3 - OPS.wb[o];
            if (tid < 64) {
                int b = tid >> 2, q = tid & 3;
                int rem[2]; int ri = 0;
#pragma unroll
                for (int p = 0; p < 4; ++p) if (p != pc && p != pt) rem[ri++] = p;
                int n  = (1 << pc) | ((q & 1) ? (1 << rem[0]) : 0)
                                   | (((q >> 1) & 1) ? (1 << rem[1]) : 0);
                int n2 = n | (1 << pt);
                float tr = Ur[b * 16 + n]; Ur[b * 16 + n] = Ur[b * 16 + n2]; Ur[b * 16 + n2] = tr;
                float ti = Ui[b * 16 + n]; Ui[b * 16 + n] = Ui[b * 16 + n2]; Ui[b * 16 + n2] = ti;
            }
        } else {  // rotation, kind/wire/weight-index compile-time
            const float th = wts[OPS.widx[o]];
            const float ch = __builtin_amdgcn_cosf(th * INV4PI);  // cos(th/2), rev units
            const float sh = __builtin_amdgcn_sinf(th * INV4PI);
            const int p = 3 - OPS.wa[o];
            if (tid < 128) {
                int b = tid >> 3, q = tid & 7;
                int low = q & ((1 << p) - 1);
                int high = (q >> p) << (p + 1);
                int n0 = high | low, n1 = n0 | (1 << p);
                float a0r = Ur[b * 16 + n0], a0i = Ui[b * 16 + n0];
                float a1r = Ur[b * 16 + n1], a1i = Ui[b * 16 + n1];
                float b0r, b0i, b1r, b1i;
                if (OPS.kind[o] == 0) {        // RX
                    b0r = ch * a0r + sh * a1i;  b0i = ch * a0i - sh * a1r;
                    b1r = sh * a0i + ch * a1r;  b1i = -sh * a0r + ch * a1i;
                } else if (OPS.kind[o] == 1) { // RY
                    b0r = ch * a0r - sh * a1r;  b0i = ch * a0i - sh * a1i;
                    b1r = sh * a0r + ch * a1r;  b1i = sh * a0i + ch * a1i;
                } else {                       // RZ
                    b0r = ch * a0r + sh * a0i;  b0i = ch * a0i - sh * a0r;
                    b1r = ch * a1r - sh * a1i;  b1i = ch * a1i + sh * a1r;
                }
                Ur[b * 16 + n0] = b0r; Ui[b * 16 + n0] = b0i;
                Ur[b * 16 + n1] = b1r; Ui[b * 16 + n1] = b1i;
            }
        }
        __syncthreads();
    }
    // Stage 2 (union-masked)
    for (int item = tid; item < NU * 16; item += 512) {
        const int t = TB.tlist[item >> 4], n = item & 15;
        const int zmask = TB.zm[t], xmask = TB.xm[t];
        float s = 0.f;
#pragma unroll
        for (int b2 = 0; b2 < 16; ++b2) {
            int bx = b2 ^ xmask;
            float sgn = (__popc(b2 & zmask) & 1) ? -1.f : 1.f;
            s += sgn * (Ur[b2 * 16 + n] * Ur[bx * 16 + n] +
                        Ui[b2 * 16 + n] * Ui[bx * 16 + n]);
        }
        S[t * 16 + n] = s;
    }
    __syncthreads();
    // Stage 3
    for (int item = tid; item < 324; item += 512) {
        const int j = item / 81, t = item % 81;
        if (!TB.mj[j][t]) continue;
        float acc = 0.f;
#pragma unroll
        for (int n = 0; n < 16; ++n) {
            float zj = ((n >> (3 - j)) & 1) ? -1.f : 1.f;
            acc += zj * S[t * 16 + n];
        }
        g_W[item] = acc * 0.0625f;
    }
}

// quanv: block = 2 output rows x 128 cols. Phase 1: block computes
// (cos pi p, sin pi p) for its 3x129x3ch input halo ONCE into LDS.
// Phase 2: per-thread masked polynomial from LDS trig values.
#define TJ 128
#define TI 2
__global__ void __launch_bounds__(256) quanv_kernel(const float* __restrict__ x,
                                                    float* __restrict__ out) {
    __shared__ float2 trig[3][3][TJ + 4];  // [ch][row][col]
    const int j0 = blockIdx.x * TJ;
    const int i0 = blockIdx.y * TI;
    const int tid = threadIdx.x;

    // Phase 1: fill trig halo. Per channel 3*129=387 items, 256 threads.
#pragma unroll
    for (int ch = 0; ch < 3; ++ch) {
        const float* xc = x + (size_t)ch * (IMGW * IMGW);
#pragma unroll
        for (int base = 0; base < 387; base += 256) {
            int idx = base + tid;
            if (idx < 387) {
                int r = (idx >= 258) ? 2 : (idx >= 129 ? 1 : 0);
                int c = idx - r * 129;
                int gi = i0 + r; if (gi > 511) gi = 511;
                int gj = j0 + c; if (gj > 511) gj = 511;
                float v = 0.5f * xc[gi * IMGW + gj];
                float2 t;
                t.x = __builtin_amdgcn_cosf(v);  // cos(pi p), rev units
                t.y = __builtin_amdgcn_sinf(v);  // sin(pi p)
                trig[ch][r][c] = t;
            }
        }
    }
    __syncthreads();

    const int lj = tid & (TJ - 1);
    const int li = tid >> 7;
    const int j = j0 + lj;
    const int i = i0 + li;

    float mon[81];
#pragma unroll
    for (int t = 0; t < 81; ++t) mon[t] = 0.f;

#pragma unroll
    for (int ch = 0; ch < 3; ++ch) {
        const float2 a00 = trig[ch][li][lj];
        const float2 a01 = trig[ch][li][lj + 1];
        const float2 a10 = trig[ch][li + 1][lj];
        const float2 a11 = trig[ch][li + 1][lj + 1];
        const float v0[3] = {1.f, a00.x, a00.y};
        const float v1[3] = {1.f, a01.x, a01.y};
        const float v2[3] = {1.f, a10.x, a10.y};
        const float v3[3] = {1.f, a11.x, a11.y};
        float m01[9], m23[9];
#pragma unroll
        for (int a = 0; a < 3; ++a)
#pragma unroll
            for (int b = 0; b < 3; ++b) {
                m01[a * 3 + b] = v0[a] * v1[b];
                m23[a * 3 + b] = v2[a] * v3[b];
            }
#pragma unroll
        for (int a = 0; a < 9; ++a)
#pragma unroll
            for (int b = 0; b < 9; ++b)
                if (TB.u[a * 9 + b])  // constexpr-folded
                    mon[a * 9 + b] = fmaf(m01[a], m23[b], mon[a * 9 + b]);
    }

    float acc0 = 0.f, acc1 = 0.f, acc2 = 0.f, acc3 = 0.f;
#pragma unroll
    for (int t = 0; t < 81; ++t) {
        if (TB.mj[0][t]) acc0 = fmaf(g_W[0 * 81 + t], mon[t], acc0);
        if (TB.mj[1][t]) acc1 = fmaf(g_W[1 * 81 + t], mon[t], acc1);
        if (TB.mj[2][t]) acc2 = fmaf(g_W[2 * 81 + t], mon[t], acc2);
        if (TB.mj[3][t]) acc3 = fmaf(g_W[3 * 81 + t], mon[t], acc3);
    }
    if (i < OUTHW && j < OUTHW) {
        float4 o = make_float4(acc0, acc1, acc2, acc3);
        *reinterpret_cast<float4*>(out + (size_t)(i * OUTHW + j) * 4) = o;
    }
}

extern "C" void kernel_launch(void* const* d_in, const int* in_sizes, int n_in,
                              void* d_out, int out_size, void* d_ws, size_t ws_size,
                              hipStream_t stream) {
    const float* x   = (const float*)d_in[0];   // [1,3,512,512] f32
    const float* wts = (const float*)d_in[1];   // [2,4] f32
    float* out = (float*)d_out;                 // [1,4,511,511] f32

    hipLaunchKernelGGL(build_table, dim3(1), dim3(512), 0, stream, wts);

    dim3 grid((OUTHW + TJ - 1) / TJ, (OUTHW + TI - 1) / TI);
    hipLaunchKernelGGL(quanv_kernel, grid, dim3(256), 0, stream, x, out);
}

// Round 6
// 12.024 us; speedup vs baseline: 1.1204x; 1.1204x over previous
//
#include <hip/hip_runtime.h>
#include <stdint.h>

#define OUTHW 511
#define IMGW 512

// ============ compile-time numpy RandomState(42) replication ============
struct COps { int n; int kind[64]; int wa[64]; int wb[64]; int widx[64]; };

struct CMT {
    uint32_t mt[624]; int mti;
    constexpr CMT(uint32_t s) : mt{}, mti(624) {
        mt[0] = s;
        for (int i = 1; i < 624; ++i)
            mt[i] = 1812433253u * (mt[i - 1] ^ (mt[i - 1] >> 30)) + (uint32_t)i;
    }
    constexpr uint32_t next32() {
        if (mti >= 624) {
            for (int i = 0; i < 624; ++i) {
                uint32_t y = (mt[i] & 0x80000000u) | (mt[(i + 1) % 624] & 0x7fffffffu);
                mt[i] = mt[(i + 397) % 624] ^ (y >> 1) ^ ((y & 1u) ? 0x9908b0dfu : 0u);
            }
            mti = 0;
        }
        uint32_t y = mt[mti++];
        y ^= y >> 11; y ^= (y << 7) & 0x9d2c5680u; y ^= (y << 15) & 0xefc60000u; y ^= y >> 18;
        return y;
    }
    constexpr double rand_double() {  // random_sample(): 2 draws
        uint32_t a = next32() >> 5, b = next32() >> 6;
        return (a * 67108864.0 + b) / 9007199254740992.0;
    }
    constexpr uint32_t interval(uint32_t mx) {  // legacy masked randint
        if (mx == 0) return 0;
        uint32_t mask = mx;
        mask |= mask >> 1; mask |= mask >> 2; mask |= mask >> 4;
        mask |= mask >> 8; mask |= mask >> 16;
        uint32_t v = next32() & mask;
        while (v > mx) v = next32() & mask;
        return v;
    }
};

constexpr COps build_ops_ce() {
    CMT mt(42u); COps P{}; P.n = 0;
    for (int l = 0; l < 2; ++l) {
        int i = 0;
        while (i < 4 && P.n < 64) {
            if (mt.rand_double() > 0.3) {
                int g = (int)mt.interval(2);  // randint(3)
                int w = (int)mt.interval(3);  // randint(4)
                P.kind[P.n] = g; P.wa[P.n] = w; P.wb[P.n] = 0; P.widx[P.n] = l * 4 + i;
                ++P.n; ++i;
            } else {  // choice(4,2,replace=False) == permutation(4)[:2]
                int arr[4] = {0, 1, 2, 3};
                for (int ii = 3; ii >= 1; --ii) {
                    int j = (int)mt.interval((uint32_t)ii);
                    int t = arr[ii]; arr[ii] = arr[j]; arr[j] = t;
                }
                P.kind[P.n] = 3; P.wa[P.n] = arr[0]; P.wb[P.n] = arr[1]; P.widx[P.n] = -1;
                ++P.n;
            }
        }
    }
    return P;
}
constexpr COps OPS = build_ops_ce();

// ===== compile-time Heisenberg support: which W_j[t] can be nonzero =====
struct Tabs {
    bool u[81];        // union support over j
    bool mj[4][81];    // per-output support
    int nu;            // |union|
    int tlist[81];     // compacted union t list
    int zm[81], xm[81];// stage-2 state-index masks per t
};

constexpr Tabs build_tabs() {
    Tabs T{};
    for (int j = 0; j < 4; ++j) {
        bool cur[256] = {};
        cur[1 << (4 + j)] = true;  // Z_j
        for (int o = OPS.n - 1; o >= 0; --o) {
            bool nxt[256] = {};
            for (int c = 0; c < 256; ++c) if (cur[c]) {
                if (OPS.kind[o] == 3) {  // CNOT: x_t ^= x_c ; z_c ^= z_t
                    int cc = OPS.wa[o], tt = OPS.wb[o], nc = c;
                    if (c & (1 << cc))       nc ^= (1 << tt);
                    if (c & (1 << (4 + tt))) nc ^= (1 << (4 + cc));
                    nxt[nc] = true;
                } else {
                    int w = OPS.wa[o];
                    int xw = (c >> w) & 1, zw = (c >> (4 + w)) & 1;
                    bool anti = false; int pm = 0;
                    if (OPS.kind[o] == 0)      { anti = zw != 0;        pm = 1 << w; }                    // RX
                    else if (OPS.kind[o] == 1) { anti = (xw ^ zw) != 0; pm = (1 << w) | (1 << (4 + w)); } // RY
                    else                       { anti = xw != 0;        pm = 1 << (4 + w); }              // RZ
                    nxt[c] = true;
                    if (anti) nxt[c ^ pm] = true;
                }
            }
            for (int c = 0; c < 256; ++c) cur[c] = nxt[c];
        }
        for (int c = 0; c < 256; ++c) if (cur[c]) {
            bool hasY = false; int t = 0;
            for (int k = 0; k < 4; ++k) {
                int xk = (c >> k) & 1, zk = (c >> (4 + k)) & 1;
                if (xk && zk) hasY = true;            // <Y> = 0 for real product state
                t = t * 3 + (zk ? 1 : (xk ? 2 : 0));  // qubit k at place 3^(3-k)
            }
            if (!hasY) { T.mj[j][t] = true; T.u[t] = true; }
        }
    }
    T.nu = 0;
    for (int t = 0; t < 81; ++t) {
        int dd[4] = {t / 27, (t / 9) % 3, (t / 3) % 3, t % 3};
        int zm = 0, xm = 0;
        for (int k = 0; k < 4; ++k) {
            int p = 3 - k;
            if (dd[k] == 1) zm |= 1 << p;
            else if (dd[k] == 2) xm |= 1 << p;
        }
        T.zm[t] = zm; T.xm[t] = xm;
        if (T.u[t]) T.tlist[T.nu++] = t;
    }
    return T;
}
constexpr Tabs TB = build_tabs();
constexpr int NU = TB.nu;

// Single fused kernel. Each block: (1) per-thread monomials (global loads
// issue first, latency hidden under table phase), (2) redundant per-block
// coefficient-table build in LDS (tiny, compile-time unrolled), (3) contract.
__global__ void __launch_bounds__(256) quanv_fused(const float* __restrict__ x,
                                                   const float* __restrict__ wts,
                                                   float* __restrict__ out) {
    __shared__ float Ur[256];     // [b*16+n] = Re U[n][b]
    __shared__ float Ui[256];
    __shared__ float S[81 * 16];  // stage-2 partials per (t,n)
    __shared__ __align__(16) float Wl[81][4];  // [t][j], zero where masked

    const int tid = threadIdx.x;
    const int j = blockIdx.x * blockDim.x + tid;
    const int i = blockIdx.y;
    const int jj = (j < OUTHW) ? j : (OUTHW - 1);  // clamp OOB lanes' loads

    // ---- Phase 1: per-thread monomials (no LDS) ----
    float mon[81];
#pragma unroll
    for (int t = 0; t < 81; ++t) mon[t] = 0.f;

#pragma unroll
    for (int c = 0; c < 3; ++c) {
        const float* xc = x + (size_t)c * (IMGW * IMGW);
        const float p00 = xc[i * IMGW + jj];
        const float p01 = xc[i * IMGW + jj + 1];
        const float p10 = xc[(i + 1) * IMGW + jj];
        const float p11 = xc[(i + 1) * IMGW + jj + 1];
        // sin(pi p) = v_sin(2pi*(p/2)): HW trig takes revolutions
        const float c0 = __builtin_amdgcn_cosf(0.5f * p00), s0 = __builtin_amdgcn_sinf(0.5f * p00);
        const float c1 = __builtin_amdgcn_cosf(0.5f * p01), s1 = __builtin_amdgcn_sinf(0.5f * p01);
        const float c2 = __builtin_amdgcn_cosf(0.5f * p10), s2 = __builtin_amdgcn_sinf(0.5f * p10);
        const float c3 = __builtin_amdgcn_cosf(0.5f * p11), s3 = __builtin_amdgcn_sinf(0.5f * p11);
        const float v0[3] = {1.f, c0, s0};
        const float v1[3] = {1.f, c1, s1};
        const float v2[3] = {1.f, c2, s2};
        const float v3[3] = {1.f, c3, s3};
        float m01[9], m23[9];
#pragma unroll
        for (int a = 0; a < 3; ++a)
#pragma unroll
            for (int b = 0; b < 3; ++b) {
                m01[a * 3 + b] = v0[a] * v1[b];
                m23[a * 3 + b] = v2[a] * v3[b];
            }
#pragma unroll
        for (int a = 0; a < 9; ++a)
#pragma unroll
            for (int b = 0; b < 9; ++b)
                if (TB.u[a * 9 + b])  // constexpr-folded
                    mon[a * 9 + b] = fmaf(m01[a], m23[b], mon[a * 9 + b]);
    }

    // ---- Phase 2: per-block table build (identical math to build_table) ----
    Ur[tid] = ((tid >> 4) == (tid & 15)) ? 1.f : 0.f;
    Ui[tid] = 0.f;
    __syncthreads();
    const float INV4PI = 0.07957747154594767f;  // 1/(4*pi)
#pragma unroll
    for (int o = 0; o < OPS.n; ++o) {
        if (OPS.kind[o] == 3) {  // CNOT — wires compile-time
            const int pc = 3 - OPS.wa[o], pt = 3 - OPS.wb[o];
            if (tid < 64) {
                int b = tid >> 2, q = tid & 3;
                int rem[2]; int ri = 0;
#pragma unroll
                for (int p = 0; p < 4; ++p) if (p != pc && p != pt) rem[ri++] = p;
                int n  = (1 << pc) | ((q & 1) ? (1 << rem[0]) : 0)
                                   | (((q >> 1) & 1) ? (1 << rem[1]) : 0);
                int n2 = n | (1 << pt);
                float tr = Ur[b * 16 + n]; Ur[b * 16 + n] = Ur[b * 16 + n2]; Ur[b * 16 + n2] = tr;
                float ti = Ui[b * 16 + n]; Ui[b * 16 + n] = Ui[b * 16 + n2]; Ui[b * 16 + n2] = ti;
            }
        } else {  // rotation, kind/wire/weight-index compile-time
            const float th = wts[OPS.widx[o]];
            const float ch = __builtin_amdgcn_cosf(th * INV4PI);  // cos(th/2), rev units
            const float sh = __builtin_amdgcn_sinf(th * INV4PI);
            const int p = 3 - OPS.wa[o];
            if (tid < 128) {
                int b = tid >> 3, q = tid & 7;
                int low = q & ((1 << p) - 1);
                int high = (q >> p) << (p + 1);
                int n0 = high | low, n1 = n0 | (1 << p);
                float a0r = Ur[b * 16 + n0], a0i = Ui[b * 16 + n0];
                float a1r = Ur[b * 16 + n1], a1i = Ui[b * 16 + n1];
                float b0r, b0i, b1r, b1i;
                if (OPS.kind[o] == 0) {        // RX
                    b0r = ch * a0r + sh * a1i;  b0i = ch * a0i - sh * a1r;
                    b1r = sh * a0i + ch * a1r;  b1i = -sh * a0r + ch * a1i;
                } else if (OPS.kind[o] == 1) { // RY
                    b0r = ch * a0r - sh * a1r;  b0i = ch * a0i - sh * a1i;
                    b1r = sh * a0r + ch * a1r;  b1i = sh * a0i + ch * a1i;
                } else {                       // RZ
                    b0r = ch * a0r + sh * a0i;  b0i = ch * a0i - sh * a0r;
                    b1r = ch * a1r - sh * a1i;  b1i = ch * a1i + sh * a1r;
                }
                Ur[b * 16 + n0] = b0r; Ui[b * 16 + n0] = b0i;
                Ur[b * 16 + n1] = b1r; Ui[b * 16 + n1] = b1i;
            }
        }
        __syncthreads();
    }
    // Stage 2 (union-masked): S[t][n]
    for (int item = tid; item < NU * 16; item += 256) {
        const int t = TB.tlist[item >> 4], n = item & 15;
        const int zmask = TB.zm[t], xmask = TB.xm[t];
        float s = 0.f;
#pragma unroll
        for (int b2 = 0; b2 < 16; ++b2) {
            int bx = b2 ^ xmask;
            float sgn = (__popc(b2 & zmask) & 1) ? -1.f : 1.f;
            s += sgn * (Ur[b2 * 16 + n] * Ur[bx * 16 + n] +
                        Ui[b2 * 16 + n] * Ui[bx * 16 + n]);
        }
        S[t * 16 + n] = s;
    }
    __syncthreads();
    // Stage 3: Wl[t][jo] = (1/16) sum_n z_jo(n) S[t][n]  (0 where masked)
    for (int item = tid; item < 324; item += 256) {
        const int jo = item / 81, t = item % 81;
        float acc = 0.f;
        if (TB.mj[jo][t]) {
#pragma unroll
            for (int n = 0; n < 16; ++n) {
                float zj = ((n >> (3 - jo)) & 1) ? -1.f : 1.f;
                acc += zj * S[t * 16 + n];
            }
            acc *= 0.0625f;
        }
        Wl[t][jo] = acc;
    }
    __syncthreads();

    // ---- Phase 3: contraction (uniform LDS address -> broadcast reads) ----
    if (j >= OUTHW) return;
    float acc0 = 0.f, acc1 = 0.f, acc2 = 0.f, acc3 = 0.f;
#pragma unroll
    for (int t = 0; t < 81; ++t) {
        if (!TB.u[t]) continue;  // constexpr-folded
        const float4 w = *reinterpret_cast<const float4*>(&Wl[t][0]);
        const float m = mon[t];
        if (TB.mj[0][t]) acc0 = fmaf(w.x, m, acc0);
        if (TB.mj[1][t]) acc1 = fmaf(w.y, m, acc1);
        if (TB.mj[2][t]) acc2 = fmaf(w.z, m, acc2);
        if (TB.mj[3][t]) acc3 = fmaf(w.w, m, acc3);
    }
    float4 o = make_float4(acc0, acc1, acc2, acc3);
    *reinterpret_cast<float4*>(out + (size_t)(i * OUTHW + j) * 4) = o;
}

extern "C" void kernel_launch(void* const* d_in, const int* in_sizes, int n_in,
                              void* d_out, int out_size, void* d_ws, size_t ws_size,
                              hipStream_t stream) {
    const float* x   = (const float*)d_in[0];   // [1,3,512,512] f32
    const float* wts = (const float*)d_in[1];   // [2,4] f32
    float* out = (float*)d_out;                 // [1,4,511,511] f32

    dim3 grid((OUTHW + 255) / 256, OUTHW);
    hipLaunchKernelGGL(quanv_fused, grid, dim3(256), 0, stream, x, wts, out);
}

// Round 7
// 11.214 us; speedup vs baseline: 1.2014x; 1.0723x over previous
//
#include <hip/hip_runtime.h>
#include <stdint.h>

#define OUTHW 511
#define IMGW 512

// ============ compile-time numpy RandomState(42) replication ============
struct COps { int n; int kind[64]; int wa[64]; int wb[64]; int widx[64]; };

struct CMT {
    uint32_t mt[624]; int mti;
    constexpr CMT(uint32_t s) : mt{}, mti(624) {
        mt[0] = s;
        for (int i = 1; i < 624; ++i)
            mt[i] = 1812433253u * (mt[i - 1] ^ (mt[i - 1] >> 30)) + (uint32_t)i;
    }
    constexpr uint32_t next32() {
        if (mti >= 624) {
            for (int i = 0; i < 624; ++i) {
                uint32_t y = (mt[i] & 0x80000000u) | (mt[(i + 1) % 624] & 0x7fffffffu);
                mt[i] = mt[(i + 397) % 624] ^ (y >> 1) ^ ((y & 1u) ? 0x9908b0dfu : 0u);
            }
            mti = 0;
        }
        uint32_t y = mt[mti++];
        y ^= y >> 11; y ^= (y << 7) & 0x9d2c5680u; y ^= (y << 15) & 0xefc60000u; y ^= y >> 18;
        return y;
    }
    constexpr double rand_double() {  // random_sample(): 2 draws
        uint32_t a = next32() >> 5, b = next32() >> 6;
        return (a * 67108864.0 + b) / 9007199254740992.0;
    }
    constexpr uint32_t interval(uint32_t mx) {  // legacy masked randint
        if (mx == 0) return 0;
        uint32_t mask = mx;
        mask |= mask >> 1; mask |= mask >> 2; mask |= mask >> 4;
        mask |= mask >> 8; mask |= mask >> 16;
        uint32_t v = next32() & mask;
        while (v > mx) v = next32() & mask;
        return v;
    }
};

constexpr COps build_ops_ce() {
    CMT mt(42u); COps P{}; P.n = 0;
    for (int l = 0; l < 2; ++l) {
        int i = 0;
        while (i < 4 && P.n < 64) {
            if (mt.rand_double() > 0.3) {
                int g = (int)mt.interval(2);  // randint(3)
                int w = (int)mt.interval(3);  // randint(4)
                P.kind[P.n] = g; P.wa[P.n] = w; P.wb[P.n] = 0; P.widx[P.n] = l * 4 + i;
                ++P.n; ++i;
            } else {  // choice(4,2,replace=False) == permutation(4)[:2]
                int arr[4] = {0, 1, 2, 3};
                for (int ii = 3; ii >= 1; --ii) {
                    int j = (int)mt.interval((uint32_t)ii);
                    int t = arr[ii]; arr[ii] = arr[j]; arr[j] = t;
                }
                P.kind[P.n] = 3; P.wa[P.n] = arr[0]; P.wb[P.n] = arr[1]; P.widx[P.n] = -1;
                ++P.n;
            }
        }
    }
    return P;
}
constexpr COps OPS = build_ops_ce();

// ===== compile-time Heisenberg support: which W_j[t] can be nonzero =====
struct Tabs {
    bool u[81];        // union support over j
    bool mj[4][81];    // per-output support
    int nu;            // |union|
    int tlist[81];     // compacted union t list
    int zm[81], xm[81];// stage-2 state-index masks per t
};

constexpr Tabs build_tabs() {
    Tabs T{};
    for (int j = 0; j < 4; ++j) {
        bool cur[256] = {};
        cur[1 << (4 + j)] = true;  // Z_j
        for (int o = OPS.n - 1; o >= 0; --o) {
            bool nxt[256] = {};
            for (int c = 0; c < 256; ++c) if (cur[c]) {
                if (OPS.kind[o] == 3) {  // CNOT: x_t ^= x_c ; z_c ^= z_t
                    int cc = OPS.wa[o], tt = OPS.wb[o], nc = c;
                    if (c & (1 << cc))       nc ^= (1 << tt);
                    if (c & (1 << (4 + tt))) nc ^= (1 << (4 + cc));
                    nxt[nc] = true;
                } else {
                    int w = OPS.wa[o];
                    int xw = (c >> w) & 1, zw = (c >> (4 + w)) & 1;
                    bool anti = false; int pm = 0;
                    if (OPS.kind[o] == 0)      { anti = zw != 0;        pm = 1 << w; }                    // RX
                    else if (OPS.kind[o] == 1) { anti = (xw ^ zw) != 0; pm = (1 << w) | (1 << (4 + w)); } // RY
                    else                       { anti = xw != 0;        pm = 1 << (4 + w); }              // RZ
                    nxt[c] = true;
                    if (anti) nxt[c ^ pm] = true;
                }
            }
            for (int c = 0; c < 256; ++c) cur[c] = nxt[c];
        }
        for (int c = 0; c < 256; ++c) if (cur[c]) {
            bool hasY = false; int t = 0;
            for (int k = 0; k < 4; ++k) {
                int xk = (c >> k) & 1, zk = (c >> (4 + k)) & 1;
                if (xk && zk) hasY = true;            // <Y> = 0 for real product state
                t = t * 3 + (zk ? 1 : (xk ? 2 : 0));  // qubit k at place 3^(3-k)
            }
            if (!hasY) { T.mj[j][t] = true; T.u[t] = true; }
        }
    }
    T.nu = 0;
    for (int t = 0; t < 81; ++t) {
        int dd[4] = {t / 27, (t / 9) % 3, (t / 3) % 3, t % 3};
        int zm = 0, xm = 0;
        for (int k = 0; k < 4; ++k) {
            int p = 3 - k;
            if (dd[k] == 1) zm |= 1 << p;
            else if (dd[k] == 2) xm |= 1 << p;
        }
        T.zm[t] = zm; T.xm[t] = xm;
        if (T.u[t]) T.tlist[T.nu++] = t;
    }
    return T;
}
constexpr Tabs TB = build_tabs();
constexpr int NU = TB.nu;

// Fused kernel, 2 output rows per thread (vertical pair shares the middle
// input row: loads 24->18, TRANS 48->36, row-products 36->27 per 2 pixels).
// Block: 256 threads = 256 cols x 2 rows; grid (2,256) = 512 blocks (halves
// redundant per-block table builds vs 1022).
__global__ void __launch_bounds__(256) quanv_fused(const float* __restrict__ x,
                                                   const float* __restrict__ wts,
                                                   float* __restrict__ out) {
    __shared__ float Ur[256];     // [b*16+n] = Re U[n][b]
    __shared__ float Ui[256];
    __shared__ float S[81 * 16];  // stage-2 partials per (t,n)
    __shared__ __align__(16) float Wl[81][4];  // [t][j], zero where masked

    const int tid = threadIdx.x;
    const int j = blockIdx.x * blockDim.x + tid;
    const int i0 = blockIdx.y * 2;             // output rows i0, i0+1
    const int jj = (j < OUTHW) ? j : (OUTHW - 1);  // clamp OOB lanes' loads
    const int r2 = (i0 + 2 <= 511) ? (i0 + 2) : 511;  // clamp bottom input row

    // ---- Phase 1: per-thread monomials for both output rows ----
    float mon1[81], mon2[81];
#pragma unroll
    for (int t = 0; t < 81; ++t) { mon1[t] = 0.f; mon2[t] = 0.f; }

#pragma unroll
    for (int c = 0; c < 3; ++c) {
        const float* xc = x + (size_t)c * (IMGW * IMGW);
        // 3 input rows x 2 cols
        const float pA0 = xc[i0 * IMGW + jj],       pA1 = xc[i0 * IMGW + jj + 1];
        const float pB0 = xc[(i0 + 1) * IMGW + jj], pB1 = xc[(i0 + 1) * IMGW + jj + 1];
        const float pC0 = xc[r2 * IMGW + jj],       pC1 = xc[r2 * IMGW + jj + 1];
        // sin(pi p) = v_sin(2pi*(p/2)): HW trig takes revolutions
        const float cA0 = __builtin_amdgcn_cosf(0.5f * pA0), sA0 = __builtin_amdgcn_sinf(0.5f * pA0);
        const float cA1 = __builtin_amdgcn_cosf(0.5f * pA1), sA1 = __builtin_amdgcn_sinf(0.5f * pA1);
        const float cB0 = __builtin_amdgcn_cosf(0.5f * pB0), sB0 = __builtin_amdgcn_sinf(0.5f * pB0);
        const float cB1 = __builtin_amdgcn_cosf(0.5f * pB1), sB1 = __builtin_amdgcn_sinf(0.5f * pB1);
        const float cC0 = __builtin_amdgcn_cosf(0.5f * pC0), sC0 = __builtin_amdgcn_sinf(0.5f * pC0);
        const float cC1 = __builtin_amdgcn_cosf(0.5f * pC1), sC1 = __builtin_amdgcn_sinf(0.5f * pC1);
        const float vA0[3] = {1.f, cA0, sA0}, vA1[3] = {1.f, cA1, sA1};
        const float vB0[3] = {1.f, cB0, sB0}, vB1[3] = {1.f, cB1, sB1};
        const float vC0[3] = {1.f, cC0, sC0}, vC1[3] = {1.f, cC1, sC1};
        // per-row 9-vectors (left-col x right-col)
        float mA[9], mB[9], mC[9];
#pragma unroll
        for (int a = 0; a < 3; ++a)
#pragma unroll
            for (int b = 0; b < 3; ++b) {
                mA[a * 3 + b] = vA0[a] * vA1[b];
                mB[a * 3 + b] = vB0[a] * vB1[b];
                mC[a * 3 + b] = vC0[a] * vC1[b];
            }
#pragma unroll
        for (int a = 0; a < 9; ++a)
#pragma unroll
            for (int b = 0; b < 9; ++b)
                if (TB.u[a * 9 + b]) {  // constexpr-folded
                    mon1[a * 9 + b] = fmaf(mA[a], mB[b], mon1[a * 9 + b]);
                    mon2[a * 9 + b] = fmaf(mB[a], mC[b], mon2[a * 9 + b]);
                }
    }

    // ---- Phase 2: per-block table build (identical math to before) ----
    Ur[tid] = ((tid >> 4) == (tid & 15)) ? 1.f : 0.f;
    Ui[tid] = 0.f;
    __syncthreads();
    const float INV4PI = 0.07957747154594767f;  // 1/(4*pi)
#pragma unroll
    for (int o = 0; o < OPS.n; ++o) {
        if (OPS.kind[o] == 3) {  // CNOT — wires compile-time
            const int pc = 3 - OPS.wa[o], pt = 3 - OPS.wb[o];
            if (tid < 64) {
                int b = tid >> 2, q = tid & 3;
                int rem[2]; int ri = 0;
#pragma unroll
                for (int p = 0; p < 4; ++p) if (p != pc && p != pt) rem[ri++] = p;
                int n  = (1 << pc) | ((q & 1) ? (1 << rem[0]) : 0)
                                   | (((q >> 1) & 1) ? (1 << rem[1]) : 0);
                int n2 = n | (1 << pt);
                float tr = Ur[b * 16 + n]; Ur[b * 16 + n] = Ur[b * 16 + n2]; Ur[b * 16 + n2] = tr;
                float ti = Ui[b * 16 + n]; Ui[b * 16 + n] = Ui[b * 16 + n2]; Ui[b * 16 + n2] = ti;
            }
        } else {  // rotation, kind/wire/weight-index compile-time
            const float th = wts[OPS.widx[o]];
            const float ch = __builtin_amdgcn_cosf(th * INV4PI);  // cos(th/2), rev units
            const float sh = __builtin_amdgcn_sinf(th * INV4PI);
            const int p = 3 - OPS.wa[o];
            if (tid < 128) {
                int b = tid >> 3, q = tid & 7;
                int low = q & ((1 << p) - 1);
                int high = (q >> p) << (p + 1);
                int n0 = high | low, n1 = n0 | (1 << p);
                float a0r = Ur[b * 16 + n0], a0i = Ui[b * 16 + n0];
                float a1r = Ur[b * 16 + n1], a1i = Ui[b * 16 + n1];
                float b0r, b0i, b1r, b1i;
                if (OPS.kind[o] == 0) {        // RX
                    b0r = ch * a0r + sh * a1i;  b0i = ch * a0i - sh * a1r;
                    b1r = sh * a0i + ch * a1r;  b1i = -sh * a0r + ch * a1i;
                } else if (OPS.kind[o] == 1) { // RY
                    b0r = ch * a0r - sh * a1r;  b0i = ch * a0i - sh * a1i;
                    b1r = sh * a0r + ch * a1r;  b1i = sh * a0i + ch * a1i;
                } else {                       // RZ
                    b0r = ch * a0r + sh * a0i;  b0i = ch * a0i - sh * a0r;
                    b1r = ch * a1r - sh * a1i;  b1i = ch * a1i + sh * a1r;
                }
                Ur[b * 16 + n0] = b0r; Ui[b * 16 + n0] = b0i;
                Ur[b * 16 + n1] = b1r; Ui[b * 16 + n1] = b1i;
            }
        }
        __syncthreads();
    }
    // Stage 2 (union-masked): S[t][n]
    for (int item = tid; item < NU * 16; item += 256) {
        const int t = TB.tlist[item >> 4], n = item & 15;
        const int zmask = TB.zm[t], xmask = TB.xm[t];
        float s = 0.f;
#pragma unroll
        for (int b2 = 0; b2 < 16; ++b2) {
            int bx = b2 ^ xmask;
            float sgn = (__popc(b2 & zmask) & 1) ? -1.f : 1.f;
            s += sgn * (Ur[b2 * 16 + n] * Ur[bx * 16 + n] +
                        Ui[b2 * 16 + n] * Ui[bx * 16 + n]);
        }
        S[t * 16 + n] = s;
    }
    __syncthreads();
    // Stage 3: Wl[t][jo] = (1/16) sum_n z_jo(n) S[t][n]  (0 where masked)
    for (int item = tid; item < 324; item += 256) {
        const int jo = item / 81, t = item % 81;
        float acc = 0.f;
        if (TB.mj[jo][t]) {
#pragma unroll
            for (int n = 0; n < 16; ++n) {
                float zj = ((n >> (3 - jo)) & 1) ? -1.f : 1.f;
                acc += zj * S[t * 16 + n];
            }
            acc *= 0.0625f;
        }
        Wl[t][jo] = acc;
    }
    __syncthreads();

    // ---- Phase 3: contraction + stores for both rows ----
    if (j >= OUTHW) return;
    float a0 = 0.f, a1 = 0.f, a2 = 0.f, a3 = 0.f;
    float b0 = 0.f, b1 = 0.f, b2 = 0.f, b3 = 0.f;
#pragma unroll
    for (int t = 0; t < 81; ++t) {
        if (!TB.u[t]) continue;  // constexpr-folded
        const float4 w = *reinterpret_cast<const float4*>(&Wl[t][0]);
        const float m1 = mon1[t], m2 = mon2[t];
        if (TB.mj[0][t]) { a0 = fmaf(w.x, m1, a0); b0 = fmaf(w.x, m2, b0); }
        if (TB.mj[1][t]) { a1 = fmaf(w.y, m1, a1); b1 = fmaf(w.y, m2, b1); }
        if (TB.mj[2][t]) { a2 = fmaf(w.z, m1, a2); b2 = fmaf(w.z, m2, b2); }
        if (TB.mj[3][t]) { a3 = fmaf(w.w, m1, a3); b3 = fmaf(w.w, m2, b3); }
    }
    *reinterpret_cast<float4*>(out + (size_t)(i0 * OUTHW + j) * 4) =
        make_float4(a0, a1, a2, a3);
    if (i0 + 1 < OUTHW)
        *reinterpret_cast<float4*>(out + (size_t)((i0 + 1) * OUTHW + j) * 4) =
            make_float4(b0, b1, b2, b3);
}

extern "C" void kernel_launch(void* const* d_in, const int* in_sizes, int n_in,
                              void* d_out, int out_size, void* d_ws, size_t ws_size,
                              hipStream_t stream) {
    const float* x   = (const float*)d_in[0];   // [1,3,512,512] f32
    const float* wts = (const float*)d_in[1];   // [2,4] f32
    float* out = (float*)d_out;                 // [1,4,511,511] f32

    dim3 grid((OUTHW + 255) / 256, (OUTHW + 1) / 2);  // (2, 256)
    hipLaunchKernelGGL(quanv_fused, grid, dim3(256), 0, stream, x, wts, out);
}